// Round 13
// baseline (14245.961 us; speedup 1.0000x reference)
//
#include <hip/hip_runtime.h>
#include <hip/hip_bf16.h>
#include <math.h>

#define Bb 64
#define Tt 1024
#define Dd 128
#define Hh 256
#define G4 1024  // 4*H
#define Vv 128
#define NVh 3
#define BT (Bb*Tt)

typedef __fp16 half2_t __attribute__((ext_vector_type(2)));
typedef __fp16 f16x4 __attribute__((ext_vector_type(4)));
typedef __fp16 f16x8 __attribute__((ext_vector_type(8)));
typedef float f32x4 __attribute__((ext_vector_type(4)));

__device__ __forceinline__ half2_t pkh(float a, float b) {
    return __builtin_amdgcn_cvt_pkrtz(a, b);
}
__device__ __forceinline__ float fdot2(half2_t a, half2_t b, float c) {
#if __has_builtin(__builtin_amdgcn_fdot2)
    return __builtin_amdgcn_fdot2(a, b, c, false);
#else
    return c + (float)a[0] * (float)b[0] + (float)a[1] * (float)b[1];
#endif
}
__device__ __forceinline__ half2_t bch(unsigned int x) {
    return __builtin_bit_cast(half2_t, x);
}
__device__ __forceinline__ float fsig(float x) {
    return __builtin_amdgcn_rcpf(1.f + __expf(-x));
}
__device__ __forceinline__ float ftanh(float x) {
    float e = __expf(-2.f * fabsf(x));
    float r = (1.f - e) * __builtin_amdgcn_rcpf(1.f + e);
    return copysignf(r, x);
}

// ---------------- Kernel 0: f32 -> f16 convert (RNE), n multiple of 4 ----------
__global__ __launch_bounds__(256) void cvt16(const float* __restrict__ in,
                                             __fp16* __restrict__ out, int n4) {
    int i = blockIdx.x * 256 + threadIdx.x;
    if (i < n4) {
        float4 v = ((const float4*)in)[i];
        f16x4 o;
        o[0] = (__fp16)v.x; o[1] = (__fp16)v.y;
        o[2] = (__fp16)v.z; o[3] = (__fp16)v.w;
        ((f16x4*)out)[i] = o;
    }
}

// ---------------- flags zeroing (stream-ordered before the scan; replay-safe) ----
__global__ void zero_flags(unsigned int* __restrict__ f) {
    f[threadIdx.x] = 0u;
}

// ---------------- Kernel A: gx via MFMA f16 (R8 form) ----------------------------
__global__ __launch_bounds__(256) void gx_mfma(const __fp16* __restrict__ x16,
                                               const __fp16* __restrict__ Wih16,
                                               const float* __restrict__ bih,
                                               const float* __restrict__ bhh,
                                               __fp16* __restrict__ gx2) {
    const int tid = threadIdx.x;
    const int w = tid >> 6, l = tid & 63;
    const int mb = blockIdx.x * 64 + w * 16;
    const int jj0 = blockIdx.y * 16;
    const int lr = l & 15, lk = l >> 4;

    f32x4 acc[4] = {};
    const __fp16* xa = x16 + (size_t)(mb + lr) * Dd + lk * 8;
    #pragma unroll
    for (int ks = 0; ks < 4; ++ks) {                 // K=128, 32 per step
        f16x8 af = *(const f16x8*)(xa + ks * 32);
        #pragma unroll
        for (int g = 0; g < 4; ++g) {
            const __fp16* bb = Wih16 + (size_t)(g * 256 + jj0 + lr) * Dd + ks * 32 + lk * 8;
            f16x8 bf = *(const f16x8*)bb;
            acc[g] = __builtin_amdgcn_mfma_f32_16x16x32_f16(af, bf, acc[g], 0, 0, 0);
        }
    }
    float bsum[4];
    #pragma unroll
    for (int g = 0; g < 4; ++g) {
        int j = g * 256 + jj0 + lr;
        bsum[g] = bih[j] + bhh[j];
    }
    #pragma unroll
    for (int r = 0; r < 4; ++r) {
        int m = mb + lk * 4 + r;                     // D row = (lane>>4)*4+reg
        f16x4 o;
        o[0] = (__fp16)(acc[0][r] + bsum[0]);
        o[1] = (__fp16)(acc[1][r] + bsum[1]);
        o[2] = (__fp16)(acc[2][r] + bsum[2]);
        o[3] = (__fp16)(acc[3][r] + bsum[3]);
        *(f16x4*)&gx2[((size_t)m * Hh + jj0 + lr) * 4] = o;
    }
}

// ---------------- Kernel B: LSTM scan, 4 CUs per sequence (v12) ------------------
// 256 blocks x 512 threads. seq = bid&63, part = bid>>6 (parts of a seq land on
// the same XCD under round-robin dispatch; correctness is dispatch-independent).
// Block computes gate rows {g*256 + part*64 + l} full-K. Wave w: gate=w&3,
// K-half=w>>2; lane l = h-index offset. W = 64 reg pairs/thread, NO LDS W.
// Per step: dot (16 uniform b128 h-reads) -> gact exchange -> wave0 epilogue
// stores 64 h f16 into hs16 (exchange buffer == output), fence, flag=t+1;
// wave1 acquire-spins on the 4 flags then loads the 512B h-row into LDS.
__global__ __launch_bounds__(512, 1) void lstm_scan4(const __fp16* __restrict__ gx2,
                                                     const float* __restrict__ Whh,
                                                     __fp16* __restrict__ hs16,
                                                     unsigned int* __restrict__ flags) {
    __shared__ __align__(16) __fp16 hsh[2][Hh];      // 1KB double buffer
    __shared__ float gact[2][4][64];                 // 2KB: [K-half][gate][idx]
    const int bid = blockIdx.x;
    const int seq = bid & 63;
    const int part = bid >> 6;
    const int tid = threadIdx.x;
    const int wv = tid >> 6;
    const int l = tid & 63;
    const int g = wv & 3;              // gate (wave-uniform)
    const int s = wv >> 2;             // K-half (wave-uniform)
    const int row = g * 256 + part * 64 + l;

    // ---- stage W row (K-half s): 64 packed-f16 pairs in regs ----
    half2_t W[64];
    {
        const float* wr = Whh + (size_t)row * Hh + s * 128;
        #pragma unroll
        for (int c = 0; c < 16; ++c) {
            float4 f0 = *(const float4*)&wr[c * 8];
            float4 f1 = *(const float4*)&wr[c * 8 + 4];
            W[c*4+0] = pkh(f0.x, f0.y);
            W[c*4+1] = pkh(f0.z, f0.w);
            W[c*4+2] = pkh(f1.x, f1.y);
            W[c*4+3] = pkh(f1.z, f1.w);
        }
    }
    if (tid < 128) ((unsigned int*)hsh[0])[tid] = 0u;   // h(-1) = 0
    float c_state = 0.f;
    unsigned int* flg = flags + seq * 4;

    const int jj = part * 64 + l;
    const __fp16* gxb = gx2 + ((size_t)seq * Tt * Hh + jj) * 4 + g;  // stride 1024/step
    __fp16* hrow = hs16 + (size_t)seq * Tt * Hh + jj;                // wave0 store
    const __fp16* hsrc = hs16 + (size_t)seq * Tt * Hh;               // wave1 load
    __syncthreads();

    float gxv = (s == 0) ? (float)gxb[0] : 0.f;
    int cur = 0;

    for (int t = 0; t < Tt; ++t) {
        // prefetch next step's gx (independent of h; s=0 waves)
        float nx = 0.f;
        if (s == 0)
            nx = (float)gxb[(size_t)(t + 1 < Tt ? t + 1 : t) * 1024];

        float a = gxv;
        const uint4* h4 = (const uint4*)hsh[cur] + (s << 4);  // 16 uint4 per K-half
        #pragma unroll
        for (int q = 0; q < 16; ++q) {
            uint4 hv = h4[q];                    // wave-uniform broadcast read
            a = fdot2(W[q*4+0], bch(hv.x), a);
            a = fdot2(W[q*4+1], bch(hv.y), a);
            a = fdot2(W[q*4+2], bch(hv.z), a);
            a = fdot2(W[q*4+3], bch(hv.w), a);
        }
        gact[s][g][l] = a;
        __syncthreads();                          // gact complete

        if (wv == 0) {
            float A0 = gact[0][0][l] + gact[1][0][l];   // gate i
            float A1 = gact[0][1][l] + gact[1][1][l];   // gate f
            float A2 = gact[0][2][l] + gact[1][2][l];   // gate g
            float A3 = gact[0][3][l] + gact[1][3][l];   // gate o
            float si = fsig(A0);
            float sf = fsig(A1);
            float tg = ftanh(A2);
            float so = fsig(A3);
            c_state = sf * c_state + si * tg;
            float hn = so * ftanh(c_state);
            hrow[(size_t)t * Hh] = (__fp16)hn;    // 64 x 2B contiguous
            __threadfence();                      // h visible device-wide
            if (l == 0)
                __hip_atomic_store(&flg[part], (unsigned int)(t + 1),
                                   __ATOMIC_RELEASE, __HIP_MEMORY_SCOPE_AGENT);
        }
        if (t + 1 < Tt) {
            if (wv == 1) {
                if (l < 4) {                      // spin on the 4 part flags
                    while (__hip_atomic_load(&flg[l], __ATOMIC_ACQUIRE,
                                             __HIP_MEMORY_SCOPE_AGENT) < (unsigned int)(t + 1))
                        __builtin_amdgcn_s_sleep(1);
                }
                if (l < 32)                       // load full 512B h-row -> LDS
                    ((uint4*)hsh[cur ^ 1])[l] =
                        *(const uint4*)(hsrc + (size_t)t * Hh + l * 8);
            }
            __syncthreads();                      // h(t) staged for step t+1
        }
        gxv = nx;
        cur ^= 1;
    }
}

// ---------------- Kernel C: head via MFMA f16 -----------------------------------
__global__ __launch_bounds__(256) void head_mfma(const __fp16* __restrict__ hs16,
                                                 const __fp16* __restrict__ hw16,
                                                 const float* __restrict__ hb,
                                                 float* __restrict__ out) {
    const int tid = threadIdx.x;
    const int w = tid >> 6, l = tid & 63;
    const int mb = blockIdx.x * 64 + w * 16;
    const int n0 = blockIdx.y * 64;                  // 4 N-tiles of 16
    const int lr = l & 15, lk = l >> 4;

    f32x4 acc[4] = {};
    const __fp16* aa = hs16 + (size_t)(mb + lr) * Hh + lk * 8;
    #pragma unroll
    for (int ks = 0; ks < 8; ++ks) {                 // K=256, 32 per step
        f16x8 af = *(const f16x8*)(aa + ks * 32);
        #pragma unroll
        for (int nt = 0; nt < 4; ++nt) {
            const __fp16* bb = hw16 + (size_t)(n0 + nt * 16 + lr) * Hh + ks * 32 + lk * 8;
            f16x8 bf = *(const f16x8*)bb;
            acc[nt] = __builtin_amdgcn_mfma_f32_16x16x32_f16(af, bf, acc[nt], 0, 0, 0);
        }
    }
    #pragma unroll
    for (int nt = 0; nt < 4; ++nt) {
        int nv = n0 + nt * 16 + lr;
        int nh = nv >> 7, v = nv & 127;
        float bv = hb[nv];
        #pragma unroll
        for (int r = 0; r < 4; ++r) {
            int m = mb + lk * 4 + r;
            out[(size_t)nh * BT * Vv + (size_t)m * Vv + v] = acc[nt][r] + bv;
        }
    }
}

extern "C" void kernel_launch(void* const* d_in, const int* in_sizes, int n_in,
                              void* d_out, int out_size, void* d_ws, size_t ws_size,
                              hipStream_t stream) {
    const float* x    = (const float*)d_in[0];
    const float* Wih  = (const float*)d_in[1];
    const float* Whh  = (const float*)d_in[2];
    const float* bih  = (const float*)d_in[3];
    const float* bhh  = (const float*)d_in[4];
    const float* hw   = (const float*)d_in[5];
    const float* hb   = (const float*)d_in[6];
    float* out = (float*)d_out;

    // workspace carve (f16): x16 | Wih16 | hw16 | gx2 | hs16 | flags (~185 MB)
    __fp16* x16   = (__fp16*)d_ws;                     // BT*128
    __fp16* Wih16 = x16 + (size_t)BT * Dd;             // 1024*128
    __fp16* hw16  = Wih16 + (size_t)G4 * Dd;           // 384*256
    __fp16* gx2   = hw16 + (size_t)NVh * Vv * Hh;      // BT*1024 (packed f16x4)
    __fp16* hs16  = gx2 + (size_t)BT * G4;             // BT*256 (scan exchange+output)
    unsigned int* flags = (unsigned int*)(hs16 + (size_t)BT * Hh);  // 256 u32

    cvt16<<<(BT * Dd / 4 + 255) / 256, 256, 0, stream>>>(x, x16, BT * Dd / 4);
    cvt16<<<(G4 * Dd / 4 + 255) / 256, 256, 0, stream>>>(Wih, Wih16, G4 * Dd / 4);
    cvt16<<<(NVh * Vv * Hh / 4 + 255) / 256, 256, 0, stream>>>(hw, hw16, NVh * Vv * Hh / 4);
    zero_flags<<<1, 256, 0, stream>>>(flags);

    gx_mfma<<<dim3(BT / 64, Hh / 16), 256, 0, stream>>>(x16, Wih16, bih, bhh, gx2);
    lstm_scan4<<<256, 512, 0, stream>>>(gx2, Whh, hs16, flags);
    head_mfma<<<dim3(BT / 64, (NVh * Vv) / 64), 256, 0, stream>>>(hs16, hw16, hb, out);
}

// Round 14
// 1866.861 us; speedup vs baseline: 7.6310x; 7.6310x over previous
//
#include <hip/hip_runtime.h>
#include <hip/hip_bf16.h>
#include <math.h>

#define Bb 64
#define Tt 1024
#define Dd 128
#define Hh 256
#define G4 1024  // 4*H
#define Vv 128
#define NVh 3
#define BT (Bb*Tt)

typedef __fp16 half2_t __attribute__((ext_vector_type(2)));
typedef __fp16 f16x4 __attribute__((ext_vector_type(4)));
typedef __fp16 f16x8 __attribute__((ext_vector_type(8)));
typedef float f32x4 __attribute__((ext_vector_type(4)));

__device__ __forceinline__ half2_t pkh(float a, float b) {
    return __builtin_amdgcn_cvt_pkrtz(a, b);
}
__device__ __forceinline__ float fdot2(half2_t a, half2_t b, float c) {
#if __has_builtin(__builtin_amdgcn_fdot2)
    return __builtin_amdgcn_fdot2(a, b, c, false);
#else
    return c + (float)a[0] * (float)b[0] + (float)a[1] * (float)b[1];
#endif
}
__device__ __forceinline__ half2_t bch(unsigned int x) {
    return __builtin_bit_cast(half2_t, x);
}
__device__ __forceinline__ unsigned int bcu(half2_t x) {
    return __builtin_bit_cast(unsigned int, x);
}
__device__ __forceinline__ float fsig(float x) {
    return __builtin_amdgcn_rcpf(1.f + __expf(-x));
}
__device__ __forceinline__ float ftanh(float x) {
    float e = __expf(-2.f * fabsf(x));
    float r = (1.f - e) * __builtin_amdgcn_rcpf(1.f + e);
    return copysignf(r, x);
}

// ---------------- Kernel 0: f32 -> f16 convert (RNE), n multiple of 4 ----------
__global__ __launch_bounds__(256) void cvt16(const float* __restrict__ in,
                                             __fp16* __restrict__ out, int n4) {
    int i = blockIdx.x * 256 + threadIdx.x;
    if (i < n4) {
        float4 v = ((const float4*)in)[i];
        f16x4 o;
        o[0] = (__fp16)v.x; o[1] = (__fp16)v.y;
        o[2] = (__fp16)v.z; o[3] = (__fp16)v.w;
        ((f16x4*)out)[i] = o;
    }
}

// ---------------- Kernel A: gx via MFMA f16 (R8 form) ----------------------------
// gx2[bt][jj][gate] (f16x4 packed) = x[bt][:]·W_ih[gate*256+jj][:] + b_ih + b_hh
__global__ __launch_bounds__(256) void gx_mfma(const __fp16* __restrict__ x16,
                                               const __fp16* __restrict__ Wih16,
                                               const float* __restrict__ bih,
                                               const float* __restrict__ bhh,
                                               __fp16* __restrict__ gx2) {
    const int tid = threadIdx.x;
    const int w = tid >> 6, l = tid & 63;
    const int mb = blockIdx.x * 64 + w * 16;
    const int jj0 = blockIdx.y * 16;
    const int lr = l & 15, lk = l >> 4;

    f32x4 acc[4] = {};
    const __fp16* xa = x16 + (size_t)(mb + lr) * Dd + lk * 8;
    #pragma unroll
    for (int ks = 0; ks < 4; ++ks) {                 // K=128, 32 per step
        f16x8 af = *(const f16x8*)(xa + ks * 32);
        #pragma unroll
        for (int g = 0; g < 4; ++g) {
            const __fp16* bb = Wih16 + (size_t)(g * 256 + jj0 + lr) * Dd + ks * 32 + lk * 8;
            f16x8 bf = *(const f16x8*)bb;
            acc[g] = __builtin_amdgcn_mfma_f32_16x16x32_f16(af, bf, acc[g], 0, 0, 0);
        }
    }
    float bsum[4];
    #pragma unroll
    for (int g = 0; g < 4; ++g) {
        int j = g * 256 + jj0 + lr;
        bsum[g] = bih[j] + bhh[j];
    }
    #pragma unroll
    for (int r = 0; r < 4; ++r) {
        int m = mb + lk * 4 + r;                     // D row = (lane>>4)*4+reg
        f16x4 o;
        o[0] = (__fp16)(acc[0][r] + bsum[0]);
        o[1] = (__fp16)(acc[1][r] + bsum[1]);
        o[2] = (__fp16)(acc[2][r] + bsum[2]);
        o[3] = (__fp16)(acc[3][r] + bsum[3]);
        *(f16x4*)&gx2[((size_t)m * Hh + jj0 + lr) * 4] = o;
    }
}

// ---------------- Kernel B: persistent LSTM scan (v13: pk_fma_f16 dot loop) ------
// R8 base: 512 thr (8 waves, 2/SIMD). Thread (jj=tid&255, s=tid>>8) owns all 4
// gate rows of h-index jj, K-half s. Gates i,f,g: w[3][64] = 192 reg pairs;
// gate o: 64 pairs in 128KB LDS. NEW: dot products via v_pk_fma_f16 (full-rate,
// 2 MACs/op in f16) with f32 flush every 16 pairs (one fdot2 with (1,1)) —
// attacks the measured VALU-issue bound (dot2 is half-rate: 2414 busy cyc/step).
__global__ __launch_bounds__(512, 2) void lstm_scan(const __fp16* __restrict__ gx2,
                                                    const float* __restrict__ Whh,
                                                    __fp16* __restrict__ hs16) {
    __shared__ __align__(16) uint4 wlds[16 * 512];   // 128KB: gate-o [q][tid]
    __shared__ __align__(16) __fp16 hsh[Hh];         // 512B
    __shared__ __align__(16) float4 pex[256];        // 4KB: s=1 partials
    const int tid = threadIdx.x;
    const int jj = tid & 255;
    const int s = tid >> 8;            // wave-uniform (waves 0-3: s=0, 4-7: s=1)
    const int b = blockIdx.x;
    const half2_t kOne = { (__fp16)1.f, (__fp16)1.f };
    const half2_t kZero = { (__fp16)0.f, (__fp16)0.f };

    // ---- stage W: gates i,f,g K-half s into regs; gate o (64 pairs) into LDS ----
    half2_t w[3][64];
    #pragma unroll
    for (int g = 0; g < 3; ++g) {
        const float* wr = Whh + (size_t)(g * 256 + jj) * Hh + s * 128;
        #pragma unroll
        for (int c = 0; c < 16; ++c) {
            float4 f0 = *(const float4*)&wr[c * 8];
            float4 f1 = *(const float4*)&wr[c * 8 + 4];
            w[g][c*4+0] = pkh(f0.x, f0.y);
            w[g][c*4+1] = pkh(f0.z, f0.w);
            w[g][c*4+2] = pkh(f1.x, f1.y);
            w[g][c*4+3] = pkh(f1.z, f1.w);
        }
    }
    {
        const float* wr3 = Whh + (size_t)(3 * 256 + jj) * Hh + s * 128;
        #pragma unroll
        for (int q = 0; q < 16; ++q) {
            float4 f0 = *(const float4*)&wr3[q * 8];
            float4 f1 = *(const float4*)&wr3[q * 8 + 4];
            uint4 o;
            o.x = bcu(pkh(f0.x, f0.y));
            o.y = bcu(pkh(f0.z, f0.w));
            o.z = bcu(pkh(f1.x, f1.y));
            o.w = bcu(pkh(f1.z, f1.w));
            wlds[q * 512 + tid] = o;
        }
    }
    if (tid < 128) ((unsigned int*)hsh)[tid] = 0u;
    float c_state = 0.f;
    __syncthreads();

    const __fp16* gxb = gx2 + ((size_t)b * Tt * Hh + jj) * 4;  // step stride 1024 f16
    __fp16* hsb = hs16 + (size_t)b * Tt * Hh + jj;             // s=0 only

    float g0 = 0.f, g1 = 0.f, g2 = 0.f, g3 = 0.f;
    if (s == 0) {
        uint2 gv = *(const uint2*)gxb;
        half2_t p = bch(gv.x), q = bch(gv.y);
        g0 = (float)p[0]; g1 = (float)p[1]; g2 = (float)q[0]; g3 = (float)q[1];
    }

    const uint4* h4 = (const uint4*)hsh + (s << 4);  // 16 uint4 per K-half
    __fp16 hprev = (__fp16)0.f;

    for (int t = 0; t < Tt; ++t) {
        // deferred h store from step t-1 (keeps vmcnt drain off barrier-2)
        if (s == 0 && t > 0) hsb[(size_t)(t - 1) * Hh] = hprev;

        // prefetch next step's gx (independent of h)
        float n0 = 0.f, n1 = 0.f, n2 = 0.f, n3 = 0.f;
        if (s == 0) {
            const __fp16* gn = gxb + (size_t)(t + 1 < Tt ? t + 1 : t) * 1024;
            uint2 gv = *(const uint2*)gn;
            half2_t p = bch(gv.x), q = bch(gv.y);
            n0 = (float)p[0]; n1 = (float)p[1]; n2 = (float)q[0]; n3 = (float)q[1];
        }

        float a0 = 0.f, a1 = 0.f, a2 = 0.f, a3 = 0.f;
        half2_t p0 = kZero, p1 = kZero, p2 = kZero, p3 = kZero;

        #pragma unroll
        for (int q = 0; q < 16; ++q) {
            uint4 hv = h4[q];                     // uniform broadcast read (K-half)
            uint4 wv = wlds[q * 512 + tid];       // lane-distinct, conflict-free
            half2_t u0 = bch(hv.x), u1 = bch(hv.y);
            half2_t u2 = bch(hv.z), u3 = bch(hv.w);
            p0 = w[0][q*4+0] * u0 + p0;  p1 = w[1][q*4+0] * u0 + p1;
            p2 = w[2][q*4+0] * u0 + p2;  p3 = bch(wv.x)   * u0 + p3;
            p0 = w[0][q*4+1] * u1 + p0;  p1 = w[1][q*4+1] * u1 + p1;
            p2 = w[2][q*4+1] * u1 + p2;  p3 = bch(wv.y)   * u1 + p3;
            p0 = w[0][q*4+2] * u2 + p0;  p1 = w[1][q*4+2] * u2 + p1;
            p2 = w[2][q*4+2] * u2 + p2;  p3 = bch(wv.z)   * u2 + p3;
            p0 = w[0][q*4+3] * u3 + p0;  p1 = w[1][q*4+3] * u3 + p1;
            p2 = w[2][q*4+3] * u3 + p2;  p3 = bch(wv.w)   * u3 + p3;
            if ((q & 3) == 3) {                   // flush f16 chunk accs to f32
                a0 = fdot2(p0, kOne, a0);  p0 = kZero;
                a1 = fdot2(p1, kOne, a1);  p1 = kZero;
                a2 = fdot2(p2, kOne, a2);  p2 = kZero;
                a3 = fdot2(p3, kOne, a3);  p3 = kZero;
            }
        }

        if (s == 1) pex[jj] = make_float4(a0, a1, a2, a3);
        __syncthreads();                 // pex visible; all hsh reads complete

        if (s == 0) {
            float4 pp = pex[jj];
            float A0 = a0 + pp.x + g0;   // gate i
            float A1 = a1 + pp.y + g1;   // gate f
            float A2 = a2 + pp.z + g2;   // gate g
            float A3 = a3 + pp.w + g3;   // gate o
            float si = fsig(A0);
            float sf = fsig(A1);
            float tg = ftanh(A2);
            float so = fsig(A3);
            c_state = sf * c_state + si * tg;
            float hn = so * ftanh(c_state);
            hprev = (__fp16)hn;
            hsh[jj] = hprev;
        }
        g0 = n0; g1 = n1; g2 = n2; g3 = n3;
        __syncthreads();                 // h(t) visible for step t+1
    }
    if (s == 0) hsb[(size_t)(Tt - 1) * Hh] = hprev;
}

// ---------------- Kernel C: head via MFMA f16 -----------------------------------
__global__ __launch_bounds__(256) void head_mfma(const __fp16* __restrict__ hs16,
                                                 const __fp16* __restrict__ hw16,
                                                 const float* __restrict__ hb,
                                                 float* __restrict__ out) {
    const int tid = threadIdx.x;
    const int w = tid >> 6, l = tid & 63;
    const int mb = blockIdx.x * 64 + w * 16;
    const int n0 = blockIdx.y * 64;                  // 4 N-tiles of 16
    const int lr = l & 15, lk = l >> 4;

    f32x4 acc[4] = {};
    const __fp16* aa = hs16 + (size_t)(mb + lr) * Hh + lk * 8;
    #pragma unroll
    for (int ks = 0; ks < 8; ++ks) {                 // K=256, 32 per step
        f16x8 af = *(const f16x8*)(aa + ks * 32);
        #pragma unroll
        for (int nt = 0; nt < 4; ++nt) {
            const __fp16* bb = hw16 + (size_t)(n0 + nt * 16 + lr) * Hh + ks * 32 + lk * 8;
            f16x8 bf = *(const f16x8*)bb;
            acc[nt] = __builtin_amdgcn_mfma_f32_16x16x32_f16(af, bf, acc[nt], 0, 0, 0);
        }
    }
    #pragma unroll
    for (int nt = 0; nt < 4; ++nt) {
        int nv = n0 + nt * 16 + lr;
        int nh = nv >> 7, v = nv & 127;
        float bv = hb[nv];
        #pragma unroll
        for (int r = 0; r < 4; ++r) {
            int m = mb + lk * 4 + r;
            out[(size_t)nh * BT * Vv + (size_t)m * Vv + v] = acc[nt][r] + bv;
        }
    }
}

extern "C" void kernel_launch(void* const* d_in, const int* in_sizes, int n_in,
                              void* d_out, int out_size, void* d_ws, size_t ws_size,
                              hipStream_t stream) {
    const float* x    = (const float*)d_in[0];
    const float* Wih  = (const float*)d_in[1];
    const float* Whh  = (const float*)d_in[2];
    const float* bih  = (const float*)d_in[3];
    const float* bhh  = (const float*)d_in[4];
    const float* hw   = (const float*)d_in[5];
    const float* hb   = (const float*)d_in[6];
    float* out = (float*)d_out;

    // workspace carve (f16): x16 | Wih16 | hw16 | gx2 | hs16  (~176 MB total)
    __fp16* x16   = (__fp16*)d_ws;                     // BT*128
    __fp16* Wih16 = x16 + (size_t)BT * Dd;             // 1024*128
    __fp16* hw16  = Wih16 + (size_t)G4 * Dd;           // 384*256
    __fp16* gx2   = hw16 + (size_t)NVh * Vv * Hh;      // BT*1024 (packed f16x4)
    __fp16* hs16  = gx2 + (size_t)BT * G4;             // BT*256

    cvt16<<<(BT * Dd / 4 + 255) / 256, 256, 0, stream>>>(x, x16, BT * Dd / 4);
    cvt16<<<(G4 * Dd / 4 + 255) / 256, 256, 0, stream>>>(Wih, Wih16, G4 * Dd / 4);
    cvt16<<<(NVh * Vv * Hh / 4 + 255) / 256, 256, 0, stream>>>(hw, hw16, NVh * Vv * Hh / 4);

    gx_mfma<<<dim3(BT / 64, Hh / 16), 256, 0, stream>>>(x16, Wih16, bih, bhh, gx2);
    lstm_scan<<<Bb, 512, 0, stream>>>(gx2, Whh, hs16);
    head_mfma<<<dim3(BT / 64, (NVh * Vv) / 64), 256, 0, stream>>>(hs16, hw16, hb, out);
}